// Round 2
// 1226.720 us; speedup vs baseline: 1.0589x; 1.0589x over previous
//
#include <hip/hip_runtime.h>
#include <hip/hip_bf16.h>

typedef unsigned short u16;
typedef __attribute__((ext_vector_type(8))) short bf16x8;
typedef __attribute__((ext_vector_type(4))) float f32x4;
typedef __attribute__((ext_vector_type(8))) unsigned short u16x8;

#define MFMA16 __builtin_amdgcn_mfma_f32_16x16x32_bf16
#define SB0() __builtin_amdgcn_sched_barrier(0)
#define BARRIER() do { SB0(); __builtin_amdgcn_s_barrier(); SB0(); } while (0)

__device__ inline u16 f2bf(float f) {
    union { float f; unsigned u; } v; v.f = f;
    unsigned u = v.u;
    u += 0x7fffu + ((u >> 16) & 1u);   // round-to-nearest-even
    return (u16)(u >> 16);
}

// async global -> LDS, 16B per lane (global_load_lds_dwordx4)
__device__ __forceinline__ void gl_lds16(const u16* g, u16* l) {
    __builtin_amdgcn_global_load_lds(
        (const __attribute__((address_space(1))) unsigned int*)g,
        (__attribute__((address_space(3))) unsigned int*)l, 16, 0, 0);
}

// ---------------- cast fp32 -> bf16, 8 elems/thread ----------------
__global__ __launch_bounds__(256) void cast_kernel(const float* __restrict__ in,
                                                   u16* __restrict__ out, int n8) {
    int i = blockIdx.x * 256 + threadIdx.x;
    if (i >= n8) return;
    const float4* p4 = (const float4*)in;
    float4 a = p4[2 * (size_t)i], b = p4[2 * (size_t)i + 1];
    u16x8 o;
    o[0] = f2bf(a.x); o[1] = f2bf(a.y); o[2] = f2bf(a.z); o[3] = f2bf(a.w);
    o[4] = f2bf(b.x); o[5] = f2bf(b.y); o[6] = f2bf(b.z); o[7] = f2bf(b.w);
    *(u16x8*)(out + 8 * (size_t)i) = o;
}

// -------- cast+transpose weights: in[K=512][N] fp32 -> out[N][512] bf16 ------
__global__ __launch_bounds__(256) void castT_kernel(const float* __restrict__ in,
                                                    u16* __restrict__ out, int N, int total) {
    int i = blockIdx.x * 256 + threadIdx.x;  // i = n*512 + k
    if (i >= total) return;
    int n = i >> 9, k = i & 511;
    out[i] = f2bf(in[(size_t)k * N + n]);    // tiny (3MB), L2-resident
}

// ======================= 256x256 8-phase MFMA GEMM =========================
// C[M,N] = A[M,K] * Bt[N,K]^T, bf16 in, BK=64, 512 threads (8 waves: 2m x 4n).
// LDS 128 KiB: double-buffered A,B tiles split in 128x64 half-tiles.
// T1 (XCD bijective swizzle) + T2 (st_16x32 LDS swizzle via pre-swizzled
// global source + swizzled ds_read) + T3/T4 (8-phase, counted vmcnt) +
// T5 (setprio around MFMA clusters).
//
// vmcnt ledger (2 loads per stage_half):
//   prologue issues 14 (t0 x4 halves, t1 x3); vmcnt(6) retires t0's 8.
//   steady iter t stages t+1.A1 (ph0), t+2.B0 (ph1), t+2.B1 (ph2), t+2.A0
//   (ph3); end-of-iter vmcnt(6) retires exactly tile t+1's 8, leaving
//   t+2's 6 in flight. Tail: vmcnt(0) at t=NT-2; no waits at t=NT-1.
// LDS safety: every region's last ds_read is drained (lgkmcnt(0)) and
//   barrier-ordered before the stage that overwrites it is issued.

// swizzled LDS read: byte ^= ((byte>>9)&1)<<5 within the [256][64] tile
__device__ __forceinline__ bf16x8 lds_frag(const u16* tile, int row, int colbyte) {
    int off = (row << 7) + colbyte;
    off ^= ((off >> 9) & 1) << 5;
    return *(const bf16x8*)((const char*)tile + off);
}

// stage one 128x64 half-tile (16 KB): 2x global_load_lds_dwordx4 per thread.
// LDS dest is LINEAR (chunk i at byte i*16); the SOURCE address carries the
// inverse swizzle (lrow/lcol precomputed from the involution) -> rule 21.
__device__ __forceinline__ void stage_half(const u16* __restrict__ X, int K,
                                           int row0, int cap, int k0,
                                           int lrow, int lcol, u16* half_, int tid) {
    int r0 = row0 + lrow;      if (r0 > cap) r0 = cap;   // ragged-M clamp
    int r1 = row0 + lrow + 64; if (r1 > cap) r1 = cap;
    gl_lds16(X + (size_t)r0 * K + k0 + lcol, half_ + tid * 8);
    gl_lds16(X + (size_t)r1 * K + k0 + lcol, half_ + (tid + 512) * 8);
}

#define QUAD_MFMA(mhh, nhh)                                                    \
    _Pragma("unroll") for (int mf2 = 0; mf2 < 4; mf2++)                        \
    _Pragma("unroll") for (int nf2 = 0; nf2 < 2; nf2++)                        \
    _Pragma("unroll") for (int ks = 0; ks < 2; ks++)                           \
        acc[(mhh)*4 + mf2][(nhh)*2 + nf2] =                                    \
            MFMA16(a[mf2*2 + ks], b[((nhh)*2 + nf2)*2 + ks],                   \
                   acc[(mhh)*4 + mf2][(nhh)*2 + nf2], 0, 0, 0);

#define LOAD_B_ALL()                                                           \
    _Pragma("unroll") for (int nf = 0; nf < 4; nf++)                           \
    _Pragma("unroll") for (int ks = 0; ks < 2; ks++)                           \
        b[nf*2 + ks] = lds_frag(Btl, wn*64 + nf*16 + l16, ks*64 + quad*16);

#define LOAD_A(mhh)                                                            \
    _Pragma("unroll") for (int mf2 = 0; mf2 < 4; mf2++)                        \
    _Pragma("unroll") for (int ks = 0; ks < 2; ks++)                           \
        a[mf2*2 + ks] = lds_frag(At, wm*128 + (mhh)*64 + mf2*16 + l16,         \
                                 ks*64 + quad*16);

template <int OUT_BF16>
__global__ __launch_bounds__(512, 2) void gemm256_kernel(const u16* __restrict__ A,
                                                         const u16* __restrict__ Bt,
                                                         void* __restrict__ Cv,
                                                         int M, int N, int K) {
    __shared__ __align__(1024) u16 As[2][16384];   // [buf][row*64+col], halves at 0 / 8192
    __shared__ __align__(1024) u16 Bs[2][16384];

    const int tid  = threadIdx.x;
    const int lane = tid & 63;
    const int wave = tid >> 6;
    const int l16  = lane & 15;
    const int quad = lane >> 4;
    const int wm   = wave >> 2;   // 0..1 -> 128 rows
    const int wn   = wave & 3;    // 0..3 -> 64 cols

    // T1: bijective XCD chunking (nwg % 8 != 0 safe), n-tile fastest
    const int tN = N >> 8;
    const int nwg = gridDim.x;
    const int orig = blockIdx.x;
    const int q = nwg >> 3, r = nwg & 7;
    const int xcd = orig & 7, lo = orig >> 3;
    const int wg = (xcd < r ? xcd * (q + 1) : r * (q + 1) + (xcd - r) * q) + lo;
    const int m0 = (wg / tN) << 8;
    const int n0 = (wg % tN) << 8;

    const int NT = K >> 6;
    const int mcap = M - 1;
    const int ncap = N - 1;      // never clamps (N % 256 == 0)

    // per-thread staging geometry: chunk i=tid (p0) covers LDS bytes [tid*16..),
    // logical position = physical ^ swizzle (involution). p1 adds exactly 64 rows
    // (physical +8192B flips bit13 of >>9, not bit0 -> same swizzle bit).
    const int soff  = tid << 4;
    const int soff2 = soff ^ (((soff >> 9) & 1) << 5);
    const int lrow  = soff2 >> 7;          // 0..63
    const int lcol  = (soff2 & 127) >> 1;  // u16 col, 16B-aligned

    // ---- prologue: stage t0.{B0,B1,A0,A1}, t1.{B0,B1,A0} (stream order) ----
    stage_half(Bt, K, n0,       ncap, 0, lrow, lcol, &Bs[0][0],    tid);
    stage_half(Bt, K, n0 + 128, ncap, 0, lrow, lcol, &Bs[0][8192], tid);
    stage_half(A,  K, m0,       mcap, 0, lrow, lcol, &As[0][0],    tid);
    stage_half(A,  K, m0 + 128, mcap, 0, lrow, lcol, &As[0][8192], tid);
    if (NT > 1) {
        stage_half(Bt, K, n0,       ncap, 64, lrow, lcol, &Bs[1][0],    tid);
        stage_half(Bt, K, n0 + 128, ncap, 64, lrow, lcol, &Bs[1][8192], tid);
        stage_half(A,  K, m0,       mcap, 64, lrow, lcol, &As[1][0],    tid);
    }

    f32x4 acc[8][4];
#pragma unroll
    for (int i = 0; i < 8; i++)
#pragma unroll
        for (int j = 0; j < 4; j++) acc[i][j] = (f32x4){0.f, 0.f, 0.f, 0.f};

    if (NT > 1) asm volatile("s_waitcnt vmcnt(6)");   // retires t0's 8 oldest of 14
    else        asm volatile("s_waitcnt vmcnt(0)");
    BARRIER();

    for (int t = 0; t < NT; ++t) {
        const u16* At  = &As[t & 1][0];
        const u16* Btl = &Bs[t & 1][0];
        bf16x8 a[8], b[8];

        // ---- phase 0: quadrant (0,0); reads ALL B + A[mh0]; stage (t+1).A1 ----
        LOAD_B_ALL();
        LOAD_A(0);
        if (t + 1 < NT)
            stage_half(A, K, m0 + 128, mcap, (t + 1) * 64, lrow, lcol,
                       &As[(t + 1) & 1][8192], tid);
        BARRIER();
        asm volatile("s_waitcnt lgkmcnt(0)");
        SB0();
        __builtin_amdgcn_s_setprio(1);
        QUAD_MFMA(0, 0);
        __builtin_amdgcn_s_setprio(0);
        BARRIER();

        // ---- phase 1: quadrant (0,1); stage (t+2).B0 (B-half0 consumed ph0) ----
        if (t + 2 < NT)
            stage_half(Bt, K, n0, ncap, (t + 2) * 64, lrow, lcol, &Bs[t & 1][0], tid);
        BARRIER();
        __builtin_amdgcn_s_setprio(1);
        QUAD_MFMA(0, 1);
        __builtin_amdgcn_s_setprio(0);
        BARRIER();

        // ---- phase 2: quadrant (1,0); reads A[mh1]; stage (t+2).B1 ----
        LOAD_A(1);
        if (t + 2 < NT)
            stage_half(Bt, K, n0 + 128, ncap, (t + 2) * 64, lrow, lcol,
                       &Bs[t & 1][8192], tid);
        BARRIER();
        asm volatile("s_waitcnt lgkmcnt(0)");
        SB0();
        __builtin_amdgcn_s_setprio(1);
        QUAD_MFMA(1, 0);
        __builtin_amdgcn_s_setprio(0);
        BARRIER();

        // ---- phase 3: quadrant (1,1); stage (t+2).A0 (A-half0 consumed ph0/ph2) ----
        if (t + 2 < NT)
            stage_half(A, K, m0, mcap, (t + 2) * 64, lrow, lcol, &As[t & 1][0], tid);
        BARRIER();
        __builtin_amdgcn_s_setprio(1);
        QUAD_MFMA(1, 1);
        __builtin_amdgcn_s_setprio(0);
        if (t + 1 < NT) {   // counted vmcnt: tile t+2's 6 loads stay in flight
            if (t + 2 < NT) asm volatile("s_waitcnt vmcnt(6)");
            else            asm volatile("s_waitcnt vmcnt(0)");
        }
        BARRIER();
    }

    // epilogue: C row = quad*4+r, col = l16 (verified layout)
#pragma unroll
    for (int mf = 0; mf < 8; mf++) {
#pragma unroll
        for (int rr = 0; rr < 4; rr++) {
            int gm = m0 + wm * 128 + mf * 16 + quad * 4 + rr;
            if (gm < M) {
#pragma unroll
                for (int nf = 0; nf < 4; nf++) {
                    int gn = n0 + wn * 64 + nf * 16 + l16;
                    if (OUT_BF16)
                        ((u16*)Cv)[(size_t)gm * N + gn] = f2bf(acc[mf][nf][rr]);
                    else
                        ((float*)Cv)[(size_t)gm * N + gn] = acc[mf][nf][rr];
                }
            }
        }
    }
}

// ---------------- fused window attention: 1 wave per (b,w,h) ----------------
__global__ __launch_bounds__(64) void attn_kernel(const u16* __restrict__ qkv,
                                                  const float* __restrict__ bias_table,
                                                  u16* __restrict__ aout) {
    __shared__ __align__(16) u16 Pm[64 * 72];    // probs bf16, stride 72
    __shared__ __align__(16) u16 VmT[32 * 72];   // V^T: [d][tok]
    __shared__ float Bi[176];                    // bias row for this head

    const int lane = threadIdx.x;
    const int l16  = lane & 15;
    const int quad = lane >> 4;
    const int h    = blockIdx.x & 15;
    const int bw   = blockIdx.x >> 4;
    const size_t qb = (size_t)bw * 49 * 1536 + h * 32;
    const size_t ob = (size_t)bw * 49 * 512 + h * 32;

    for (int t = lane; t < 169; t += 64) Bi[t] = bias_table[t * 16 + h];
    for (int t = lane; t < 32 * 16; t += 64) {
        int d = t >> 4, tok = 48 + (t & 15);
        VmT[d * 72 + tok] = 0;
    }

    const bf16x8 z8 = {0, 0, 0, 0, 0, 0, 0, 0};
    const f32x4 zf = {0.f, 0.f, 0.f, 0.f};

    bf16x8 qf[4], kf[4];
#pragma unroll
    for (int t = 0; t < 4; t++) {
        int m = t * 16 + l16;
        bool v = m < 49;
        qf[t] = v ? *(const bf16x8*)(qkv + qb + (size_t)m * 1536 + quad * 8) : z8;
        kf[t] = v ? *(const bf16x8*)(qkv + qb + 512 + (size_t)m * 1536 + quad * 8) : z8;
        if (v) {
            u16x8 v8 = *(const u16x8*)(qkv + qb + 1024 + (size_t)m * 1536 + quad * 8);
#pragma unroll
            for (int jj = 0; jj < 8; jj++) VmT[(quad * 8 + jj) * 72 + m] = v8[jj];
        }
    }

    f32x4 s[4][4];
#pragma unroll
    for (int mt = 0; mt < 4; mt++)
#pragma unroll
        for (int nt = 0; nt < 4; nt++) s[mt][nt] = MFMA16(qf[mt], kf[nt], zf, 0, 0, 0);

#pragma unroll
    for (int nt = 0; nt < 4; nt++) {
        int j = nt * 16 + l16;
        int rj = j / 7, cj = j - rj * 7;
#pragma unroll
        for (int mt = 0; mt < 4; mt++) {
#pragma unroll
            for (int r = 0; r < 4; r++) {
                int i = mt * 16 + quad * 4 + r;
                if (j >= 49) {
                    s[mt][nt][r] = -1e30f;
                } else {
                    float val = s[mt][nt][r] * 0.17677669529663687f;
                    if (i < 49) {
                        int ri = i / 7, ci = i - ri * 7;
                        val += Bi[(ri - rj + 6) * 13 + (ci - cj + 6)];
                    }
                    s[mt][nt][r] = val;
                }
            }
        }
    }

    float rsum[4][4];
#pragma unroll
    for (int mt = 0; mt < 4; mt++) {
#pragma unroll
        for (int r = 0; r < 4; r++) {
            float mx = fmaxf(fmaxf(s[mt][0][r], s[mt][1][r]), fmaxf(s[mt][2][r], s[mt][3][r]));
#pragma unroll
            for (int d = 1; d < 16; d <<= 1) mx = fmaxf(mx, __shfl_xor(mx, d, 64));
            float sum = 0.f;
#pragma unroll
            for (int nt = 0; nt < 4; nt++) {
                float e = __expf(s[mt][nt][r] - mx);
                s[mt][nt][r] = e;
                sum += e;
            }
#pragma unroll
            for (int d = 1; d < 16; d <<= 1) sum += __shfl_xor(sum, d, 64);
            rsum[mt][r] = sum;
            int row = mt * 16 + quad * 4 + r;
#pragma unroll
            for (int nt = 0; nt < 4; nt++)
                Pm[row * 72 + nt * 16 + l16] = f2bf(s[mt][nt][r]);
        }
    }
    __syncthreads();

    bf16x8 vf[2][2];
#pragma unroll
    for (int ks = 0; ks < 2; ks++)
#pragma unroll
        for (int nt = 0; nt < 2; nt++)
            vf[ks][nt] = *(const bf16x8*)(&VmT[(nt * 16 + l16) * 72 + ks * 32 + quad * 8]);

    f32x4 o[4][2];
#pragma unroll
    for (int mt = 0; mt < 4; mt++) { o[mt][0] = zf; o[mt][1] = zf; }
#pragma unroll
    for (int mt = 0; mt < 4; mt++) {
#pragma unroll
        for (int ks = 0; ks < 2; ks++) {
            bf16x8 p = *(const bf16x8*)(&Pm[(mt * 16 + l16) * 72 + ks * 32 + quad * 8]);
            o[mt][0] = MFMA16(p, vf[ks][0], o[mt][0], 0, 0, 0);
            o[mt][1] = MFMA16(p, vf[ks][1], o[mt][1], 0, 0, 0);
        }
    }

#pragma unroll
    for (int mt = 0; mt < 4; mt++) {
#pragma unroll
        for (int r = 0; r < 4; r++) {
            int i = mt * 16 + quad * 4 + r;
            if (i < 49) {
                float inv = 1.f / rsum[mt][r];
#pragma unroll
                for (int nt = 0; nt < 2; nt++)
                    aout[ob + (size_t)i * 512 + nt * 16 + l16] = f2bf(o[mt][nt][r] * inv);
            }
        }
    }
}

extern "C" void kernel_launch(void* const* d_in, const int* in_sizes, int n_in,
                              void* d_out, int out_size, void* d_ws, size_t ws_size,
                              hipStream_t stream) {
    const float* x          = (const float*)d_in[0];  // [16,196,49,512]
    const float* w_qkv      = (const float*)d_in[1];  // [512,1536]
    const float* bias_table = (const float*)d_in[2];  // [169,16]
    const float* w_out      = (const float*)d_in[3];  // [512,512]
    float* out = (float*)d_out;

    // workspace: xb | qkvb | wqkvT | woutT ; attn-out reuses xb
    char* ws = (char*)d_ws;
    u16* xb    = (u16*)ws;                                           // 157,351,936 B
    u16* qkvb  = (u16*)(ws + 157351936LL);                           // 472,055,808 B
    u16* wqkvT = (u16*)(ws + 157351936LL + 472055808LL);             // 1,572,864 B
    u16* woutT = (u16*)(ws + 157351936LL + 472055808LL + 1572864LL); // 524,288 B
    u16* aob   = xb;  // xb dead after GEMM1

    cast_kernel<<<38416, 256, 0, stream>>>(x, xb, 9834496);
    castT_kernel<<<3072, 256, 0, stream>>>(w_qkv, wqkvT, 1536, 786432);
    castT_kernel<<<1024, 256, 0, stream>>>(w_out, woutT, 512, 262144);

    // qkv = x @ w_qkv   [153664,512]x[512,1536] -> bf16; 601 m-tiles x 6 n-tiles
    gemm256_kernel<1><<<dim3(601 * 6), 512, 0, stream>>>(xb, wqkvT, qkvb, 153664, 1536, 512);

    // windowed attention, 1 wave per (b,w,h)
    attn_kernel<<<50176, 64, 0, stream>>>(qkvb, bias_table, aob);

    // out = attn_out @ w_out   [153664,512]x[512,512] -> fp32; 601 x 2 tiles
    gemm256_kernel<0><<<dim3(601 * 2), 512, 0, stream>>>(aob, woutT, out, 153664, 512, 512);
}

// Round 3
// 1205.740 us; speedup vs baseline: 1.0774x; 1.0174x over previous
//
#include <hip/hip_runtime.h>
#include <hip/hip_bf16.h>

typedef unsigned short u16;
typedef __attribute__((ext_vector_type(8))) short bf16x8;
typedef __attribute__((ext_vector_type(4))) float f32x4;
typedef __attribute__((ext_vector_type(8))) unsigned short u16x8;

#define MFMA16 __builtin_amdgcn_mfma_f32_16x16x32_bf16
#define SB0() __builtin_amdgcn_sched_barrier(0)
#define BARRIER() do { SB0(); __builtin_amdgcn_s_barrier(); SB0(); } while (0)

__device__ inline u16 f2bf(float f) {
    union { float f; unsigned u; } v; v.f = f;
    unsigned u = v.u;
    u += 0x7fffu + ((u >> 16) & 1u);   // round-to-nearest-even
    return (u16)(u >> 16);
}

// async global -> LDS, 16B per lane (global_load_lds_dwordx4)
__device__ __forceinline__ void gl_lds16(const u16* g, u16* l) {
    __builtin_amdgcn_global_load_lds(
        (const __attribute__((address_space(1))) unsigned int*)g,
        (__attribute__((address_space(3))) unsigned int*)l, 16, 0, 0);
}

// ---------------- cast fp32 -> bf16, 8 elems/thread ----------------
__global__ __launch_bounds__(256) void cast_kernel(const float* __restrict__ in,
                                                   u16* __restrict__ out, int n8) {
    int i = blockIdx.x * 256 + threadIdx.x;
    if (i >= n8) return;
    const float4* p4 = (const float4*)in;
    float4 a = p4[2 * (size_t)i], b = p4[2 * (size_t)i + 1];
    u16x8 o;
    o[0] = f2bf(a.x); o[1] = f2bf(a.y); o[2] = f2bf(a.z); o[3] = f2bf(a.w);
    o[4] = f2bf(b.x); o[5] = f2bf(b.y); o[6] = f2bf(b.z); o[7] = f2bf(b.w);
    *(u16x8*)(out + 8 * (size_t)i) = o;
}

// -------- cast+transpose weights: in[K=512][N] fp32 -> out[N][512] bf16 ------
__global__ __launch_bounds__(256) void castT_kernel(const float* __restrict__ in,
                                                    u16* __restrict__ out, int N, int total) {
    int i = blockIdx.x * 256 + threadIdx.x;  // i = n*512 + k
    if (i >= total) return;
    int n = i >> 9, k = i & 511;
    out[i] = f2bf(in[(size_t)k * N + n]);    // tiny (3MB), L2-resident
}

// ======================= 256x256 8-phase MFMA GEMM =========================
// C[M,N] = A[M,K] * Bt[N,K]^T, bf16 in, BK=64, 512 threads (8 waves: 2m x 4n).
// LDS 128 KiB: double-buffered A,B tiles split in 128x64 half-tiles.
// T1 (XCD bijective swizzle) + T2 (3-bit LDS swizzle via pre-swizzled global
// source + swizzled ds_read) + T3/T4 (8-phase, counted vmcnt) + T5 (setprio).
//
// T2 swizzle (round 3): off ^= (off>>3)&0x70 — XORs row bits 0-2 (offset bits
// 7-9, row stride 128B) into 16B-slot bits 4-6. Fragment reads (16 same-quad
// lanes = 16 consecutive rows at one slot) then spread across all 8 slots,
// 2 lanes/slot = free (m136). The 1-bit variant left a 4-way conflict
// (measured: 2.2e7 SQ_LDS_BANK_CONFLICT, ~4 extra cyc per wave ds_read).
// Involution; preserves bits 7-9, so source-side lrow/lcol pairing and the
// "+8192B = +64 rows" staging property are unchanged.
//
// vmcnt ledger (2 loads per stage_half):
//   prologue issues 14 (t0 x4 halves, t1 x3); vmcnt(6) retires t0's 8.
//   steady iter t stages t+1.A1 (ph0), t+2.B0 (ph1), t+2.B1 (ph2), t+2.A0
//   (ph3); end-of-iter vmcnt(6) retires exactly tile t+1's 8, leaving
//   t+2's 6 in flight. Tail: vmcnt(0) at t=NT-2; no waits at t=NT-1.
// LDS safety: every region's last ds_read is drained (lgkmcnt(0)) and
//   barrier-ordered before the stage that overwrites it is issued.

__device__ __forceinline__ int swz(int off) { return off ^ ((off >> 3) & 0x70); }

// swizzled LDS read
__device__ __forceinline__ bf16x8 lds_frag(const u16* tile, int row, int colbyte) {
    int off = swz((row << 7) + colbyte);
    return *(const bf16x8*)((const char*)tile + off);
}

// stage one 128x64 half-tile (16 KB): 2x global_load_lds_dwordx4 per thread.
// LDS dest is LINEAR (chunk i at byte i*16); the SOURCE address carries the
// inverse swizzle (lrow/lcol precomputed from the involution) -> rule 21.
__device__ __forceinline__ void stage_half(const u16* __restrict__ X, int K,
                                           int row0, int cap, int k0,
                                           int lrow, int lcol, u16* half_, int tid) {
    int r0 = row0 + lrow;      if (r0 > cap) r0 = cap;   // ragged-M clamp
    int r1 = row0 + lrow + 64; if (r1 > cap) r1 = cap;
    gl_lds16(X + (size_t)r0 * K + k0 + lcol, half_ + tid * 8);
    gl_lds16(X + (size_t)r1 * K + k0 + lcol, half_ + (tid + 512) * 8);
}

#define QUAD_MFMA(mhh, nhh)                                                    \
    _Pragma("unroll") for (int mf2 = 0; mf2 < 4; mf2++)                        \
    _Pragma("unroll") for (int nf2 = 0; nf2 < 2; nf2++)                        \
    _Pragma("unroll") for (int ks = 0; ks < 2; ks++)                           \
        acc[(mhh)*4 + mf2][(nhh)*2 + nf2] =                                    \
            MFMA16(a[mf2*2 + ks], b[((nhh)*2 + nf2)*2 + ks],                   \
                   acc[(mhh)*4 + mf2][(nhh)*2 + nf2], 0, 0, 0);

#define LOAD_B_ALL()                                                           \
    _Pragma("unroll") for (int nf = 0; nf < 4; nf++)                           \
    _Pragma("unroll") for (int ks = 0; ks < 2; ks++)                           \
        b[nf*2 + ks] = lds_frag(Btl, wn*64 + nf*16 + l16, ks*64 + quad*16);

#define LOAD_A(mhh)                                                            \
    _Pragma("unroll") for (int mf2 = 0; mf2 < 4; mf2++)                        \
    _Pragma("unroll") for (int ks = 0; ks < 2; ks++)                           \
        a[mf2*2 + ks] = lds_frag(At, wm*128 + (mhh)*64 + mf2*16 + l16,         \
                                 ks*64 + quad*16);

template <int OUT_BF16>
__global__ __launch_bounds__(512, 2) void gemm256_kernel(const u16* __restrict__ A,
                                                         const u16* __restrict__ Bt,
                                                         void* __restrict__ Cv,
                                                         int M, int N, int K) {
    __shared__ __align__(1024) u16 As[2][16384];   // [buf][row*64+col], halves at 0 / 8192
    __shared__ __align__(1024) u16 Bs[2][16384];

    const int tid  = threadIdx.x;
    const int lane = tid & 63;
    const int wave = tid >> 6;
    const int l16  = lane & 15;
    const int quad = lane >> 4;
    const int wm   = wave >> 2;   // 0..1 -> 128 rows
    const int wn   = wave & 3;    // 0..3 -> 64 cols

    // T1: bijective XCD chunking (nwg % 8 != 0 safe), n-tile fastest
    const int tN = N >> 8;
    const int nwg = gridDim.x;
    const int orig = blockIdx.x;
    const int q = nwg >> 3, r = nwg & 7;
    const int xcd = orig & 7, lo = orig >> 3;
    const int wg = (xcd < r ? xcd * (q + 1) : r * (q + 1) + (xcd - r) * q) + lo;
    const int m0 = (wg / tN) << 8;
    const int n0 = (wg % tN) << 8;

    const int NT = K >> 6;
    const int mcap = M - 1;
    const int ncap = N - 1;      // never clamps (N % 256 == 0)

    // per-thread staging geometry: chunk i=tid (p0) covers LDS bytes [tid*16..),
    // logical position = physical ^ swizzle (involution). p1 adds exactly 64 rows
    // (physical +8192B flips bit13, swizzle reads only bits 7-9 -> unchanged).
    const int soff  = tid << 4;
    const int soff2 = swz(soff);
    const int lrow  = soff2 >> 7;          // 0..63 (== soff>>7; bits 7+ preserved)
    const int lcol  = (soff2 & 127) >> 1;  // u16 col, 16B-aligned slot within row

    // ---- prologue: stage t0.{B0,B1,A0,A1}, t1.{B0,B1,A0} (stream order) ----
    stage_half(Bt, K, n0,       ncap, 0, lrow, lcol, &Bs[0][0],    tid);
    stage_half(Bt, K, n0 + 128, ncap, 0, lrow, lcol, &Bs[0][8192], tid);
    stage_half(A,  K, m0,       mcap, 0, lrow, lcol, &As[0][0],    tid);
    stage_half(A,  K, m0 + 128, mcap, 0, lrow, lcol, &As[0][8192], tid);
    if (NT > 1) {
        stage_half(Bt, K, n0,       ncap, 64, lrow, lcol, &Bs[1][0],    tid);
        stage_half(Bt, K, n0 + 128, ncap, 64, lrow, lcol, &Bs[1][8192], tid);
        stage_half(A,  K, m0,       mcap, 64, lrow, lcol, &As[1][0],    tid);
    }

    f32x4 acc[8][4];
#pragma unroll
    for (int i = 0; i < 8; i++)
#pragma unroll
        for (int j = 0; j < 4; j++) acc[i][j] = (f32x4){0.f, 0.f, 0.f, 0.f};

    if (NT > 1) asm volatile("s_waitcnt vmcnt(6)");   // retires t0's 8 oldest of 14
    else        asm volatile("s_waitcnt vmcnt(0)");
    BARRIER();

    for (int t = 0; t < NT; ++t) {
        const u16* At  = &As[t & 1][0];
        const u16* Btl = &Bs[t & 1][0];
        bf16x8 a[8], b[8];

        // ---- phase 0: quadrant (0,0); reads ALL B + A[mh0]; stage (t+1).A1 ----
        LOAD_B_ALL();
        LOAD_A(0);
        if (t + 1 < NT)
            stage_half(A, K, m0 + 128, mcap, (t + 1) * 64, lrow, lcol,
                       &As[(t + 1) & 1][8192], tid);
        BARRIER();
        asm volatile("s_waitcnt lgkmcnt(0)");
        SB0();
        __builtin_amdgcn_s_setprio(1);
        QUAD_MFMA(0, 0);
        __builtin_amdgcn_s_setprio(0);
        BARRIER();

        // ---- phase 1: quadrant (0,1); stage (t+2).B0 (B-half0 consumed ph0) ----
        if (t + 2 < NT)
            stage_half(Bt, K, n0, ncap, (t + 2) * 64, lrow, lcol, &Bs[t & 1][0], tid);
        BARRIER();
        __builtin_amdgcn_s_setprio(1);
        QUAD_MFMA(0, 1);
        __builtin_amdgcn_s_setprio(0);
        BARRIER();

        // ---- phase 2: quadrant (1,0); reads A[mh1]; stage (t+2).B1 ----
        LOAD_A(1);
        if (t + 2 < NT)
            stage_half(Bt, K, n0 + 128, ncap, (t + 2) * 64, lrow, lcol,
                       &Bs[t & 1][8192], tid);
        BARRIER();
        asm volatile("s_waitcnt lgkmcnt(0)");
        SB0();
        __builtin_amdgcn_s_setprio(1);
        QUAD_MFMA(1, 0);
        __builtin_amdgcn_s_setprio(0);
        BARRIER();

        // ---- phase 3: quadrant (1,1); stage (t+2).A0 (A-half0 consumed ph0/ph2) ----
        if (t + 2 < NT)
            stage_half(A, K, m0, mcap, (t + 2) * 64, lrow, lcol, &As[t & 1][0], tid);
        BARRIER();
        __builtin_amdgcn_s_setprio(1);
        QUAD_MFMA(1, 1);
        __builtin_amdgcn_s_setprio(0);
        if (t + 1 < NT) {   // counted vmcnt: tile t+2's 6 loads stay in flight
            if (t + 2 < NT) asm volatile("s_waitcnt vmcnt(6)");
            else            asm volatile("s_waitcnt vmcnt(0)");
        }
        BARRIER();
    }

    // epilogue: C row = quad*4+r, col = l16 (verified layout)
#pragma unroll
    for (int mf = 0; mf < 8; mf++) {
#pragma unroll
        for (int rr = 0; rr < 4; rr++) {
            int gm = m0 + wm * 128 + mf * 16 + quad * 4 + rr;
            if (gm < M) {
#pragma unroll
                for (int nf = 0; nf < 4; nf++) {
                    int gn = n0 + wn * 64 + nf * 16 + l16;
                    if (OUT_BF16)
                        ((u16*)Cv)[(size_t)gm * N + gn] = f2bf(acc[mf][nf][rr]);
                    else
                        ((float*)Cv)[(size_t)gm * N + gn] = acc[mf][nf][rr];
                }
            }
        }
    }
}

// ---------------- fused window attention: 1 wave per (b,w,h) ----------------
__global__ __launch_bounds__(64) void attn_kernel(const u16* __restrict__ qkv,
                                                  const float* __restrict__ bias_table,
                                                  u16* __restrict__ aout) {
    __shared__ __align__(16) u16 Pm[64 * 72];    // probs bf16, stride 72
    __shared__ __align__(16) u16 VmT[32 * 72];   // V^T: [d][tok]
    __shared__ float Bi[176];                    // bias row for this head

    const int lane = threadIdx.x;
    const int l16  = lane & 15;
    const int quad = lane >> 4;
    const int h    = blockIdx.x & 15;
    const int bw   = blockIdx.x >> 4;
    const size_t qb = (size_t)bw * 49 * 1536 + h * 32;
    const size_t ob = (size_t)bw * 49 * 512 + h * 32;

    for (int t = lane; t < 169; t += 64) Bi[t] = bias_table[t * 16 + h];
    for (int t = lane; t < 32 * 16; t += 64) {
        int d = t >> 4, tok = 48 + (t & 15);
        VmT[d * 72 + tok] = 0;
    }

    const bf16x8 z8 = {0, 0, 0, 0, 0, 0, 0, 0};
    const f32x4 zf = {0.f, 0.f, 0.f, 0.f};

    bf16x8 qf[4], kf[4];
#pragma unroll
    for (int t = 0; t < 4; t++) {
        int m = t * 16 + l16;
        bool v = m < 49;
        qf[t] = v ? *(const bf16x8*)(qkv + qb + (size_t)m * 1536 + quad * 8) : z8;
        kf[t] = v ? *(const bf16x8*)(qkv + qb + 512 + (size_t)m * 1536 + quad * 8) : z8;
        if (v) {
            u16x8 v8 = *(const u16x8*)(qkv + qb + 1024 + (size_t)m * 1536 + quad * 8);
#pragma unroll
            for (int jj = 0; jj < 8; jj++) VmT[(quad * 8 + jj) * 72 + m] = v8[jj];
        }
    }

    f32x4 s[4][4];
#pragma unroll
    for (int mt = 0; mt < 4; mt++)
#pragma unroll
        for (int nt = 0; nt < 4; nt++) s[mt][nt] = MFMA16(qf[mt], kf[nt], zf, 0, 0, 0);

#pragma unroll
    for (int nt = 0; nt < 4; nt++) {
        int j = nt * 16 + l16;
        int rj = j / 7, cj = j - rj * 7;
#pragma unroll
        for (int mt = 0; mt < 4; mt++) {
#pragma unroll
            for (int r = 0; r < 4; r++) {
                int i = mt * 16 + quad * 4 + r;
                if (j >= 49) {
                    s[mt][nt][r] = -1e30f;
                } else {
                    float val = s[mt][nt][r] * 0.17677669529663687f;
                    if (i < 49) {
                        int ri = i / 7, ci = i - ri * 7;
                        val += Bi[(ri - rj + 6) * 13 + (ci - cj + 6)];
                    }
                    s[mt][nt][r] = val;
                }
            }
        }
    }

    float rsum[4][4];
#pragma unroll
    for (int mt = 0; mt < 4; mt++) {
#pragma unroll
        for (int r = 0; r < 4; r++) {
            float mx = fmaxf(fmaxf(s[mt][0][r], s[mt][1][r]), fmaxf(s[mt][2][r], s[mt][3][r]));
#pragma unroll
            for (int d = 1; d < 16; d <<= 1) mx = fmaxf(mx, __shfl_xor(mx, d, 64));
            float sum = 0.f;
#pragma unroll
            for (int nt = 0; nt < 4; nt++) {
                float e = __expf(s[mt][nt][r] - mx);
                s[mt][nt][r] = e;
                sum += e;
            }
#pragma unroll
            for (int d = 1; d < 16; d <<= 1) sum += __shfl_xor(sum, d, 64);
            rsum[mt][r] = sum;
            int row = mt * 16 + quad * 4 + r;
#pragma unroll
            for (int nt = 0; nt < 4; nt++)
                Pm[row * 72 + nt * 16 + l16] = f2bf(s[mt][nt][r]);
        }
    }
    __syncthreads();

    bf16x8 vf[2][2];
#pragma unroll
    for (int ks = 0; ks < 2; ks++)
#pragma unroll
        for (int nt = 0; nt < 2; nt++)
            vf[ks][nt] = *(const bf16x8*)(&VmT[(nt * 16 + l16) * 72 + ks * 32 + quad * 8]);

    f32x4 o[4][2];
#pragma unroll
    for (int mt = 0; mt < 4; mt++) { o[mt][0] = zf; o[mt][1] = zf; }
#pragma unroll
    for (int mt = 0; mt < 4; mt++) {
#pragma unroll
        for (int ks = 0; ks < 2; ks++) {
            bf16x8 p = *(const bf16x8*)(&Pm[(mt * 16 + l16) * 72 + ks * 32 + quad * 8]);
            o[mt][0] = MFMA16(p, vf[ks][0], o[mt][0], 0, 0, 0);
            o[mt][1] = MFMA16(p, vf[ks][1], o[mt][1], 0, 0, 0);
        }
    }

#pragma unroll
    for (int mt = 0; mt < 4; mt++) {
#pragma unroll
        for (int r = 0; r < 4; r++) {
            int i = mt * 16 + quad * 4 + r;
            if (i < 49) {
                float inv = 1.f / rsum[mt][r];
#pragma unroll
                for (int nt = 0; nt < 2; nt++)
                    aout[ob + (size_t)i * 512 + nt * 16 + l16] = f2bf(o[mt][nt][r] * inv);
            }
        }
    }
}

extern "C" void kernel_launch(void* const* d_in, const int* in_sizes, int n_in,
                              void* d_out, int out_size, void* d_ws, size_t ws_size,
                              hipStream_t stream) {
    const float* x          = (const float*)d_in[0];  // [16,196,49,512]
    const float* w_qkv      = (const float*)d_in[1];  // [512,1536]
    const float* bias_table = (const float*)d_in[2];  // [169,16]
    const float* w_out      = (const float*)d_in[3];  // [512,512]
    float* out = (float*)d_out;

    // workspace: xb | qkvb | wqkvT | woutT ; attn-out reuses xb
    char* ws = (char*)d_ws;
    u16* xb    = (u16*)ws;                                           // 157,351,936 B
    u16* qkvb  = (u16*)(ws + 157351936LL);                           // 472,055,808 B
    u16* wqkvT = (u16*)(ws + 157351936LL + 472055808LL);             // 1,572,864 B
    u16* woutT = (u16*)(ws + 157351936LL + 472055808LL + 1572864LL); // 524,288 B
    u16* aob   = xb;  // xb dead after GEMM1

    cast_kernel<<<38416, 256, 0, stream>>>(x, xb, 9834496);
    castT_kernel<<<3072, 256, 0, stream>>>(w_qkv, wqkvT, 1536, 786432);
    castT_kernel<<<1024, 256, 0, stream>>>(w_out, woutT, 512, 262144);

    // qkv = x @ w_qkv   [153664,512]x[512,1536] -> bf16; 601 m-tiles x 6 n-tiles
    gemm256_kernel<1><<<dim3(601 * 6), 512, 0, stream>>>(xb, wqkvT, qkvb, 153664, 1536, 512);

    // windowed attention, 1 wave per (b,w,h)
    attn_kernel<<<50176, 64, 0, stream>>>(qkvb, bias_table, aob);

    // out = attn_out @ w_out   [153664,512]x[512,512] -> fp32; 601 x 2 tiles
    gemm256_kernel<0><<<dim3(601 * 2), 512, 0, stream>>>(aob, woutT, out, 153664, 512, 512);
}